// Round 4
// baseline (166.176 us; speedup 1.0000x reference)
//
#include <hip/hip_runtime.h>
#include <hip/hip_bf16.h>

// Problem constants
#define B    32
#define P    576     // 24*24 patches
#define D    768
#define K1   17      // K+1 prototypes
#define KFG  16
#define C    200
#define LN_EPS 1e-6f

typedef __attribute__((ext_vector_type(8))) short short8;   // 8 bf16 (4 VGPRs)
typedef __attribute__((ext_vector_type(4))) float f32x4;

__device__ inline unsigned short f2b(float f) {   // fp32 -> bf16 RNE
    union { float f; unsigned u; } x; x.f = f;
    unsigned r = x.u + 0x7FFF + ((x.u >> 16) & 1);
    return (unsigned short)(r >> 16);
}

// ---------------- k_pre: psq[k] + proto fp32 -> bf16 into ws ----------------
// grid 17 blocks x 256; block = one prototype row.
__global__ __launch_bounds__(256) void k_pre(const float* __restrict__ proto,
                                             float* __restrict__ psq,
                                             unsigned short* __restrict__ pbf) {
    const int k = blockIdx.x, t = threadIdx.x;
    float a0 = proto[k * D + t], a1 = proto[k * D + t + 256], a2 = proto[k * D + t + 512];
    pbf[k * D + t]       = f2b(a0);
    pbf[k * D + t + 256] = f2b(a1);
    pbf[k * D + t + 512] = f2b(a2);
    float s = a0 * a0 + a1 * a1 + a2 * a2;
    #pragma unroll
    for (int o = 1; o < 64; o <<= 1) s += __shfl_xor(s, o, 64);
    __shared__ float r[4];
    if ((t & 63) == 0) r[t >> 6] = s;
    __syncthreads();
    if (t == 0) psq[k] = r[0] + r[1] + r[2] + r[3];
}

// ---------------- k_dots: MFMA dots + softmax, K-split 4 ----------------
// grid (36 ptiles, 32 b) x 256 threads. Block owns a 16-patch M-tile;
// wave wv computes the D/4 K-range [wv*192, wv*192+192). No x/proto LDS,
// no barriers in the K-loop; one barrier to reduce K-split partials.
__global__ __launch_bounds__(256, 4) void k_dots(const float* __restrict__ x,
                                                 const unsigned short* __restrict__ pbf,
                                                 const float* __restrict__ psq,
                                                 float* __restrict__ A_out,
                                                 float* __restrict__ apool) {
    __shared__ float scL[4][64][8];   // 8 KB: [wave][lane][acc0:4 | acc1:4]
    const int tile = blockIdx.x, b = blockIdx.y;
    const int t = threadIdx.x, wv = t >> 6, lane = t & 63;
    const int n = lane & 15, kq = lane >> 4;     // n = proto col / patch row sel
    const int p0 = tile * 16;

    const float*          arow = x   + ((size_t)(b * P + p0 + n)) * D + wv * 192 + kq * 8;
    const unsigned short* brow = pbf + (size_t)n  * D + wv * 192 + kq * 8;
    const unsigned short* brw6 = pbf + (size_t)16 * D + wv * 192 + kq * 8;

    f32x4 acc0 = {0.f, 0.f, 0.f, 0.f};   // protos 0..15
    f32x4 acc1 = {0.f, 0.f, 0.f, 0.f};   // proto 16 (broadcast B)

    #pragma unroll
    for (int it = 0; it < 6; ++it) {
        const float* ap = arow + it * 32;
        float4 v0 = *(const float4*)(ap);
        float4 v1 = *(const float4*)(ap + 4);
        short8 A;
        A[0] = (short)f2b(v0.x); A[1] = (short)f2b(v0.y);
        A[2] = (short)f2b(v0.z); A[3] = (short)f2b(v0.w);
        A[4] = (short)f2b(v1.x); A[5] = (short)f2b(v1.y);
        A[6] = (short)f2b(v1.z); A[7] = (short)f2b(v1.w);
        short8 Bv = *(const short8*)(brow + it * 32);
        short8 B6 = *(const short8*)(brw6 + it * 32);
        acc0 = __builtin_amdgcn_mfma_f32_16x16x32_bf16(A, Bv, acc0, 0, 0, 0);
        acc1 = __builtin_amdgcn_mfma_f32_16x16x32_bf16(A, B6, acc1, 0, 0, 0);
    }

    #pragma unroll
    for (int r = 0; r < 4; ++r) {
        scL[wv][lane][r]     = acc0[r];
        scL[wv][lane][r + 4] = acc1[r];
    }
    __syncthreads();
    if (wv != 0) return;

    // ---- reduce K-split partials (lane holds: patches p0+kq*4+r, proto n) ----
    float s0[4], s1[4];
    #pragma unroll
    for (int r = 0; r < 4; ++r) {
        s0[r] = scL[0][lane][r]   + scL[1][lane][r]   + scL[2][lane][r]   + scL[3][lane][r];
        s1[r] = scL[0][lane][r+4] + scL[1][lane][r+4] + scL[2][lane][r+4] + scL[3][lane][r+4];
    }

    // ---- softmax across n (16-lane butterfly) + the k=16 term (uniform in n) ----
    const float pq   = psq[n];
    const float pq16 = psq[16];
    float a_[4], a16[4], ap_[4];
    #pragma unroll
    for (int r = 0; r < 4; ++r) {
        float l0  = 2.f * s0[r] - pq;
        float l16 = 2.f * s1[r] - pq16;
        float mx = l0;
        #pragma unroll
        for (int o = 1; o < 16; o <<= 1) mx = fmaxf(mx, __shfl_xor(mx, o, 64));
        mx = fmaxf(mx, l16);
        float e0  = __expf(l0 - mx);
        float e16 = __expf(l16 - mx);
        float sum = e0;
        #pragma unroll
        for (int o = 1; o < 16; o <<= 1) sum += __shfl_xor(sum, o, 64);
        sum += e16;
        const float inv = 1.f / sum;
        a_[r]  = e0 * inv;
        a16[r] = e16 * inv;
        ap_[r] = a_[r] * (1.f / (float)P);
    }

    // A_out rows 0..15: one float4 per lane (16B aligned, line-covering)
    *(float4*)(A_out + ((size_t)b * K1 + n) * P + p0 + kq * 4) =
        make_float4(a_[0], a_[1], a_[2], a_[3]);
    // A_out row 16: lane n==0 of each quad
    if (n == 0)
        *(float4*)(A_out + ((size_t)b * K1 + 16) * P + p0 + kq * 4) =
            make_float4(a16[0], a16[1], a16[2], a16[3]);
    // apool[b][p][n] = a/P  (per (kq,r): 16 lanes cover one 64B line)
    #pragma unroll
    for (int r = 0; r < 4; ++r)
        apool[((size_t)b * P + p0 + kq * 4 + r) * KFG + n] = ap_[r];
}

// ---------------- k_pool: fp32 pooling, 3 p-splits of 192 ----------------
// grid (3 dchunk, 3 psplit, 32 b) x 256; thread owns one d.
__global__ __launch_bounds__(256, 4) void k_pool(const float* __restrict__ x,
                                                 const float* __restrict__ apool,
                                                 float* __restrict__ vpart) {
    __shared__ float as_[192 * 16];   // 12.3 KB
    const int dc = blockIdx.x, psl = blockIdx.y, b = blockIdx.z;
    const int t = threadIdx.x;

    const float* asrc = apool + ((size_t)b * P + psl * 192) * KFG;
    for (int i = t; i < 192 * 16; i += 256) as_[i] = asrc[i];
    __syncthreads();

    const int d = dc * 256 + t;
    const float* xp = x + ((size_t)b * P + psl * 192) * D + d;

    float acc[KFG];
    #pragma unroll
    for (int k = 0; k < KFG; ++k) acc[k] = 0.f;

    #pragma unroll 2
    for (int p = 0; p < 192; ++p) {
        float xv = xp[(size_t)p * D];
        float4 A0 = *(const float4*)(as_ + p * 16);
        float4 A1 = *(const float4*)(as_ + p * 16 + 4);
        float4 A2 = *(const float4*)(as_ + p * 16 + 8);
        float4 A3 = *(const float4*)(as_ + p * 16 + 12);
        acc[0]  += A0.x * xv; acc[1]  += A0.y * xv; acc[2]  += A0.z * xv; acc[3]  += A0.w * xv;
        acc[4]  += A1.x * xv; acc[5]  += A1.y * xv; acc[6]  += A1.z * xv; acc[7]  += A1.w * xv;
        acc[8]  += A2.x * xv; acc[9]  += A2.y * xv; acc[10] += A2.z * xv; acc[11] += A2.w * xv;
        acc[12] += A3.x * xv; acc[13] += A3.y * xv; acc[14] += A3.z * xv; acc[15] += A3.w * xv;
    }
    float* o = vpart + ((size_t)(psl * B + b) * KFG) * D + d;
    #pragma unroll
    for (int k = 0; k < KFG; ++k) o[(size_t)k * D] = acc[k];
}

// ---------------- k_ln: reduce 3 p-splits + LayerNorm ----------------
// grid (16 k, 32 b) x 256; thread owns 3 d's.
__global__ __launch_bounds__(256) void k_ln(const float* __restrict__ vpart,
                                            const float* __restrict__ gamma,
                                            const float* __restrict__ beta,
                                            float* __restrict__ vnorm_out) {
    const int k = blockIdx.x, b = blockIdx.y, t = threadIdx.x;
    const int lane = t & 63, wv = t >> 6;

    float v[3]; float s1 = 0.f, s2 = 0.f;
    #pragma unroll
    for (int j = 0; j < 3; ++j) {
        const int d = t + j * 256;
        float s = vpart[((size_t)(0 * B + b) * KFG + k) * D + d]
                + vpart[((size_t)(1 * B + b) * KFG + k) * D + d]
                + vpart[((size_t)(2 * B + b) * KFG + k) * D + d];
        v[j] = s; s1 += s; s2 += s * s;
    }
    #pragma unroll
    for (int o = 1; o < 64; o <<= 1) {
        s1 += __shfl_xor(s1, o, 64);
        s2 += __shfl_xor(s2, o, 64);
    }
    __shared__ float r1[4], r2[4];
    if (lane == 0) { r1[wv] = s1; r2[wv] = s2; }
    __syncthreads();
    s1 = r1[0] + r1[1] + r1[2] + r1[3];
    s2 = r2[0] + r2[1] + r2[2] + r2[3];

    const float mean = s1 * (1.f / (float)D);
    const float var  = s2 * (1.f / (float)D) - mean * mean;
    const float rs   = rsqrtf(var + LN_EPS);

    #pragma unroll
    for (int j = 0; j < 3; ++j) {
        const int d = t + j * 256;
        float vn = (v[j] - mean) * rs * gamma[d] + beta[d];
        vnorm_out[((size_t)b * KFG + k) * D + d] = vn;
    }
}

// ---------------- k_cls: classifier partial GEMV over a d-range ----------------
// grid (8 d-splits of 96, 32 b) x 256; thread = class c.
__global__ __launch_bounds__(256) void k_cls(const float* __restrict__ vnorm,
                                             const float* __restrict__ W,
                                             float* __restrict__ lpart) {
    __shared__ float vs_[96 * 16];    // [d_local][k]
    const int dq = blockIdx.x, b = blockIdx.y;
    const int c = threadIdx.x;

    for (int i = c; i < 96 * 16; i += 256) {
        int k = i / 96, dd = i - k * 96;
        vs_[dd * 16 + k] = vnorm[((size_t)b * KFG + k) * D + dq * 96 + dd];
    }
    __syncthreads();

    const int cc = c < C ? c : (C - 1);
    const float* Wp = W + (size_t)dq * 96 * C + cc;

    float acc[KFG];
    #pragma unroll
    for (int k = 0; k < KFG; ++k) acc[k] = 0.f;

    #pragma unroll 2
    for (int i = 0; i < 96; ++i) {
        float wl = Wp[(size_t)i * C];
        float4 V0 = *(const float4*)(vs_ + i * 16);
        float4 V1 = *(const float4*)(vs_ + i * 16 + 4);
        float4 V2 = *(const float4*)(vs_ + i * 16 + 8);
        float4 V3 = *(const float4*)(vs_ + i * 16 + 12);
        acc[0]  += V0.x * wl; acc[1]  += V0.y * wl; acc[2]  += V0.z * wl; acc[3]  += V0.w * wl;
        acc[4]  += V1.x * wl; acc[5]  += V1.y * wl; acc[6]  += V1.z * wl; acc[7]  += V1.w * wl;
        acc[8]  += V2.x * wl; acc[9]  += V2.y * wl; acc[10] += V2.z * wl; acc[11] += V2.w * wl;
        acc[12] += V3.x * wl; acc[13] += V3.y * wl; acc[14] += V3.z * wl; acc[15] += V3.w * wl;
    }
    if (c < C) {
        float* o = lpart + ((size_t)(dq * B + b) * KFG) * C + c;
        #pragma unroll
        for (int k = 0; k < KFG; ++k) o[(size_t)k * C] = acc[k];
    }
}

// ---------------- k_comb: combine d-splits + bias; logits_parts + logits_agg ----------------
__global__ __launch_bounds__(256) void k_comb(const float* __restrict__ lpart,
                                              const float* __restrict__ bcls,
                                              float* __restrict__ parts,
                                              float* __restrict__ agg) {
    const int b = blockIdx.x, c = threadIdx.x;
    if (c >= C) return;
    const float bc = bcls[c];
    float s_agg = 0.f;
    #pragma unroll
    for (int k = 0; k < KFG; ++k) {
        float s = bc;
        #pragma unroll
        for (int dq = 0; dq < 8; ++dq)
            s += lpart[((size_t)(dq * B + b) * KFG + k) * C + c];
        parts[((size_t)b * KFG + k) * C + c] = s;
        s_agg += s;
    }
    agg[(size_t)b * C + c] = s_agg * (1.f / (float)KFG);
}

extern "C" void kernel_launch(void* const* d_in, const int* in_sizes, int n_in,
                              void* d_out, int out_size, void* d_ws, size_t ws_size,
                              hipStream_t stream) {
    const float* x     = (const float*)d_in[0];   // (32,24,24,768)
    const float* proto = (const float*)d_in[1];   // (17,768)
    const float* gamma = (const float*)d_in[2];   // (768)
    const float* beta  = (const float*)d_in[3];   // (768)
    const float* W     = (const float*)d_in[4];   // (768,200)
    const float* bcls  = (const float*)d_in[5];   // (200)

    float* out = (float*)d_out;
    float* A_out     = out;                       // 32*17*576   = 313344
    float* vnorm_out = out + 313344;              // 32*16*768   = 393216
    float* parts_out = out + 706560;              // 32*16*200   = 102400
    float* agg_out   = out + 808960;              // 32*200      = 6400

    float* ws = (float*)d_ws;
    float* psq  = ws;                              // 17 (pad 32)
    unsigned short* pbf = (unsigned short*)(ws + 32);  // 17*768 bf16 = 6528 floats-worth
    float* apool = ws + 32 + 6528;                 // 32*576*16 = 294912
    float* vpart = apool + 294912;                 // 3*32*16*768 = 1179648
    float* lpart = vpart + 1179648;                // 8*32*16*200 = 819200

    hipLaunchKernelGGL(k_pre,  dim3(K1),        dim3(256), 0, stream, proto, psq, pbf);
    hipLaunchKernelGGL(k_dots, dim3(36, B),     dim3(256), 0, stream, x, pbf, psq, A_out, apool);
    hipLaunchKernelGGL(k_pool, dim3(3, 3, B),   dim3(256), 0, stream, x, apool, vpart);
    hipLaunchKernelGGL(k_ln,   dim3(KFG, B),    dim3(256), 0, stream, vpart, gamma, beta, vnorm_out);
    hipLaunchKernelGGL(k_cls,  dim3(8, B),      dim3(256), 0, stream, vnorm_out, W, lpart);
    hipLaunchKernelGGL(k_comb, dim3(B),         dim3(256), 0, stream, lpart, bcls, parts_out, agg_out);
}

// Round 5
// 147.844 us; speedup vs baseline: 1.1240x; 1.1240x over previous
//
#include <hip/hip_runtime.h>
#include <hip/hip_bf16.h>

// Problem constants
#define B    32
#define P    576     // 24*24 patches
#define D    768
#define K1   17      // K+1 prototypes
#define KFG  16
#define C    200
#define LN_EPS 1e-6f

typedef __attribute__((ext_vector_type(8))) short short8;   // 8 bf16 (4 VGPRs)
typedef __attribute__((ext_vector_type(4))) float f32x4;

__device__ inline unsigned short f2b(float f) {   // fp32 -> bf16 RNE (scalar)
    union { float f; unsigned u; } x; x.f = f;
    unsigned r = x.u + 0x7FFF + ((x.u >> 16) & 1);
    return (unsigned short)(r >> 16);
}

// packed fp32x8 -> bf16x8 via v_cvt_pk_bf16_f32
__device__ inline short8 cvt8(float4 a, float4 b) {
    union { unsigned u[4]; short8 s; } r;
    union { __hip_bfloat162 h; unsigned u; } c;
    c.h = __float22bfloat162_rn(make_float2(a.x, a.y)); r.u[0] = c.u;
    c.h = __float22bfloat162_rn(make_float2(a.z, a.w)); r.u[1] = c.u;
    c.h = __float22bfloat162_rn(make_float2(b.x, b.y)); r.u[2] = c.u;
    c.h = __float22bfloat162_rn(make_float2(b.z, b.w)); r.u[3] = c.u;
    return r.s;
}

// ---------------- k_pre: psq[k] + proto fp32 -> bf16 into ws ----------------
__global__ __launch_bounds__(256) void k_pre(const float* __restrict__ proto,
                                             float* __restrict__ psq,
                                             unsigned short* __restrict__ pbf) {
    const int k = blockIdx.x, t = threadIdx.x;
    float a0 = proto[k * D + t], a1 = proto[k * D + t + 256], a2 = proto[k * D + t + 512];
    pbf[k * D + t]       = f2b(a0);
    pbf[k * D + t + 256] = f2b(a1);
    pbf[k * D + t + 512] = f2b(a2);
    float s = a0 * a0 + a1 * a1 + a2 * a2;
    #pragma unroll
    for (int o = 1; o < 64; o <<= 1) s += __shfl_xor(s, o, 64);
    __shared__ float r[4];
    if ((t & 63) == 0) r[t >> 6] = s;
    __syncthreads();
    if (t == 0) psq[k] = r[0] + r[1] + r[2] + r[3];
}

// ---------------- k_dots: full-K MFMA dots + softmax, one wave per 16 patches ----------------
// grid (36 ptiles, 32 b) x 64 threads. No LDS, no barriers, no idle waves.
// A-frag: x fp32 direct (per row-quad the 4 kq-lanes' 2x16B loads cover 64B
// contiguous), packed-convert to bf16. B-frag: pbf bf16 (L2-hot, 16B loads).
__global__ __launch_bounds__(64, 2) void k_dots(const float* __restrict__ x,
                                                const unsigned short* __restrict__ pbf,
                                                const float* __restrict__ psq,
                                                float* __restrict__ A_out,
                                                float* __restrict__ apool) {
    const int tile = blockIdx.x, b = blockIdx.y;
    const int lane = threadIdx.x;
    const int n = lane & 15, kq = lane >> 4;
    const int p0 = tile * 16;

    const float*          arow = x   + ((size_t)(b * P + p0 + n)) * D + kq * 8;
    const unsigned short* brow = pbf + (size_t)n  * D + kq * 8;
    const unsigned short* brw6 = pbf + (size_t)16 * D + kq * 8;

    f32x4 acc0 = {0.f, 0.f, 0.f, 0.f};   // protos 0..15
    f32x4 acc1 = {0.f, 0.f, 0.f, 0.f};   // proto 16 (broadcast B)

    #pragma unroll 8
    for (int s = 0; s < 24; ++s) {
        const float* ap = arow + s * 32;
        float4 v0 = *(const float4*)(ap);
        float4 v1 = *(const float4*)(ap + 4);
        short8 A  = cvt8(v0, v1);
        short8 Bv = *(const short8*)(brow + s * 32);
        short8 B6 = *(const short8*)(brw6 + s * 32);
        acc0 = __builtin_amdgcn_mfma_f32_16x16x32_bf16(A, Bv, acc0, 0, 0, 0);
        acc1 = __builtin_amdgcn_mfma_f32_16x16x32_bf16(A, B6, acc1, 0, 0, 0);
    }

    // ---- softmax per (kq, r) over n (16-lane butterfly; xor<16 stays in-quad) ----
    const float pq = psq[n], pq16 = psq[16];
    float a_[4], a16[4];
    #pragma unroll
    for (int r = 0; r < 4; ++r) {
        float l0  = 2.f * acc0[r] - pq;
        float l16 = 2.f * acc1[r] - pq16;
        float mx = l0;
        #pragma unroll
        for (int o = 1; o < 16; o <<= 1) mx = fmaxf(mx, __shfl_xor(mx, o, 64));
        mx = fmaxf(mx, l16);
        float e0  = __expf(l0 - mx);
        float e16 = __expf(l16 - mx);
        float sum = e0;
        #pragma unroll
        for (int o = 1; o < 16; o <<= 1) sum += __shfl_xor(sum, o, 64);
        sum += e16;
        const float inv = 1.f / sum;
        a_[r]  = e0 * inv;
        a16[r] = e16 * inv;
    }

    // A_out rows 0..15: per n, the 4 kq-lanes' float4s cover 64B contiguous
    *(float4*)(A_out + ((size_t)b * K1 + n) * P + p0 + kq * 4) =
        make_float4(a_[0], a_[1], a_[2], a_[3]);
    if (n == 0)
        *(float4*)(A_out + ((size_t)b * K1 + 16) * P + p0 + kq * 4) =
            make_float4(a16[0], a16[1], a16[2], a16[3]);

    const float invP = 1.f / (float)P;
    #pragma unroll
    for (int r = 0; r < 4; ++r)
        apool[((size_t)b * P + p0 + kq * 4 + r) * KFG + n] = a_[r] * invP;
}

// ---------------- k_pool: fp32 pooling, a-rows via uniform loads (s_load path) ----------------
// grid (3 dchunk, 6 psplit of 96, 32 b) x 256; thread owns one d. ZERO LDS.
__global__ __launch_bounds__(256, 4) void k_pool(const float* __restrict__ x,
                                                 const float* __restrict__ apool,
                                                 float* __restrict__ vpart) {
    const int dc = blockIdx.x, psl = blockIdx.y, b = blockIdx.z;
    const int t = threadIdx.x;
    const int d = dc * 256 + t;

    const float* aw = apool + ((size_t)b * P + psl * 96) * KFG;   // wave-uniform
    const float* xp = x + ((size_t)b * P + psl * 96) * D + d;

    float acc[KFG];
    #pragma unroll
    for (int k = 0; k < KFG; ++k) acc[k] = 0.f;

    #pragma unroll 4
    for (int p = 0; p < 96; ++p) {
        float xv = xp[(size_t)p * D];
        f32x4 A0 = *(const f32x4*)(aw + p * 16);        // uniform -> scalar loads
        f32x4 A1 = *(const f32x4*)(aw + p * 16 + 4);
        f32x4 A2 = *(const f32x4*)(aw + p * 16 + 8);
        f32x4 A3 = *(const f32x4*)(aw + p * 16 + 12);
        acc[0]  += A0[0] * xv; acc[1]  += A0[1] * xv; acc[2]  += A0[2] * xv; acc[3]  += A0[3] * xv;
        acc[4]  += A1[0] * xv; acc[5]  += A1[1] * xv; acc[6]  += A1[2] * xv; acc[7]  += A1[3] * xv;
        acc[8]  += A2[0] * xv; acc[9]  += A2[1] * xv; acc[10] += A2[2] * xv; acc[11] += A2[3] * xv;
        acc[12] += A3[0] * xv; acc[13] += A3[1] * xv; acc[14] += A3[2] * xv; acc[15] += A3[3] * xv;
    }
    float* o = vpart + ((size_t)(psl * B + b) * KFG) * D + d;
    #pragma unroll
    for (int k = 0; k < KFG; ++k) o[(size_t)k * D] = acc[k];
}

// ---------------- k_ln: reduce 6 p-splits + LayerNorm; write vnorm + vT ----------------
// grid (16 k, 32 b) x 256; thread owns 3 d's.
__global__ __launch_bounds__(256) void k_ln(const float* __restrict__ vpart,
                                            const float* __restrict__ gamma,
                                            const float* __restrict__ beta,
                                            float* __restrict__ vnorm_out,
                                            float* __restrict__ vT) {
    const int k = blockIdx.x, b = blockIdx.y, t = threadIdx.x;
    const int lane = t & 63, wv = t >> 6;

    float v[3]; float s1 = 0.f, s2 = 0.f;
    #pragma unroll
    for (int j = 0; j < 3; ++j) {
        const int d = t + j * 256;
        float s = 0.f;
        #pragma unroll
        for (int psl = 0; psl < 6; ++psl)
            s += vpart[((size_t)(psl * B + b) * KFG + k) * D + d];
        v[j] = s; s1 += s; s2 += s * s;
    }
    #pragma unroll
    for (int o = 1; o < 64; o <<= 1) {
        s1 += __shfl_xor(s1, o, 64);
        s2 += __shfl_xor(s2, o, 64);
    }
    __shared__ float r1[4], r2[4];
    if (lane == 0) { r1[wv] = s1; r2[wv] = s2; }
    __syncthreads();
    s1 = r1[0] + r1[1] + r1[2] + r1[3];
    s2 = r2[0] + r2[1] + r2[2] + r2[3];

    const float mean = s1 * (1.f / (float)D);
    const float var  = s2 * (1.f / (float)D) - mean * mean;
    const float rs   = rsqrtf(var + LN_EPS);

    #pragma unroll
    for (int j = 0; j < 3; ++j) {
        const int d = t + j * 256;
        float vn = (v[j] - mean) * rs * gamma[d] + beta[d];
        vnorm_out[((size_t)b * KFG + k) * D + d] = vn;
        vT[((size_t)b * D + d) * KFG + k] = vn;   // k-contiguous for k_cls s_loads
    }
}

// ---------------- k_cls: classifier partial GEMV; v-rows via uniform s_load ----------------
// grid (8 d-splits of 96, 32 b) x 256; thread = class c. ZERO LDS.
__global__ __launch_bounds__(256) void k_cls(const float* __restrict__ vT,
                                             const float* __restrict__ W,
                                             float* __restrict__ lpart) {
    const int dq = blockIdx.x, b = blockIdx.y;
    const int c = threadIdx.x;
    const int cc = c < C ? c : (C - 1);

    const float* vt = vT + ((size_t)b * D + dq * 96) * KFG;   // wave-uniform rows
    const float* Wp = W + (size_t)dq * 96 * C + cc;

    float acc[KFG];
    #pragma unroll
    for (int k = 0; k < KFG; ++k) acc[k] = 0.f;

    #pragma unroll 4
    for (int i = 0; i < 96; ++i) {
        float wl = Wp[(size_t)i * C];                 // coalesced across lanes
        f32x4 V0 = *(const f32x4*)(vt + i * 16);      // uniform -> s_load_dwordx16
        f32x4 V1 = *(const f32x4*)(vt + i * 16 + 4);
        f32x4 V2 = *(const f32x4*)(vt + i * 16 + 8);
        f32x4 V3 = *(const f32x4*)(vt + i * 16 + 12);
        acc[0]  += V0[0] * wl; acc[1]  += V0[1] * wl; acc[2]  += V0[2] * wl; acc[3]  += V0[3] * wl;
        acc[4]  += V1[0] * wl; acc[5]  += V1[1] * wl; acc[6]  += V1[2] * wl; acc[7]  += V1[3] * wl;
        acc[8]  += V2[0] * wl; acc[9]  += V2[1] * wl; acc[10] += V2[2] * wl; acc[11] += V2[3] * wl;
        acc[12] += V3[0] * wl; acc[13] += V3[1] * wl; acc[14] += V3[2] * wl; acc[15] += V3[3] * wl;
    }
    if (c < C) {
        float* o = lpart + ((size_t)(dq * B + b) * KFG) * C + c;
        #pragma unroll
        for (int k = 0; k < KFG; ++k) o[(size_t)k * C] = acc[k];
    }
}

// ---------------- k_comb: combine d-splits + bias; logits_parts + logits_agg ----------------
__global__ __launch_bounds__(256) void k_comb(const float* __restrict__ lpart,
                                              const float* __restrict__ bcls,
                                              float* __restrict__ parts,
                                              float* __restrict__ agg) {
    const int b = blockIdx.x, c = threadIdx.x;
    if (c >= C) return;
    const float bc = bcls[c];
    float s_agg = 0.f;
    #pragma unroll
    for (int k = 0; k < KFG; ++k) {
        float s = bc;
        #pragma unroll
        for (int dq = 0; dq < 8; ++dq)
            s += lpart[((size_t)(dq * B + b) * KFG + k) * C + c];
        parts[((size_t)b * KFG + k) * C + c] = s;
        s_agg += s;
    }
    agg[(size_t)b * C + c] = s_agg * (1.f / (float)KFG);
}

extern "C" void kernel_launch(void* const* d_in, const int* in_sizes, int n_in,
                              void* d_out, int out_size, void* d_ws, size_t ws_size,
                              hipStream_t stream) {
    const float* x     = (const float*)d_in[0];   // (32,24,24,768)
    const float* proto = (const float*)d_in[1];   // (17,768)
    const float* gamma = (const float*)d_in[2];   // (768)
    const float* beta  = (const float*)d_in[3];   // (768)
    const float* W     = (const float*)d_in[4];   // (768,200)
    const float* bcls  = (const float*)d_in[5];   // (200)

    float* out = (float*)d_out;
    float* A_out     = out;                       // 32*17*576   = 313344
    float* vnorm_out = out + 313344;              // 32*16*768   = 393216
    float* parts_out = out + 706560;              // 32*16*200   = 102400
    float* agg_out   = out + 808960;              // 32*200      = 6400

    float* ws = (float*)d_ws;
    float* psq  = ws;                                  // 17 (pad 32)
    unsigned short* pbf = (unsigned short*)(ws + 32);  // 17*768 bf16 (reserve 6528 floats)
    float* apool = ws + 32 + 6528;                     // 32*576*16   = 294912
    float* vpart = apool + 294912;                     // 6*32*16*768 = 2359296
    float* vT    = vpart + 2359296;                    // 32*768*16   = 393216
    float* lpart = vT + 393216;                        // 8*32*16*200 = 819200

    hipLaunchKernelGGL(k_pre,  dim3(K1),        dim3(256), 0, stream, proto, psq, pbf);
    hipLaunchKernelGGL(k_dots, dim3(36, B),     dim3(64),  0, stream, x, pbf, psq, A_out, apool);
    hipLaunchKernelGGL(k_pool, dim3(3, 6, B),   dim3(256), 0, stream, x, apool, vpart);
    hipLaunchKernelGGL(k_ln,   dim3(KFG, B),    dim3(256), 0, stream, vpart, gamma, beta, vnorm_out, vT);
    hipLaunchKernelGGL(k_cls,  dim3(8, B),      dim3(256), 0, stream, vT, W, lpart);
    hipLaunchKernelGGL(k_comb, dim3(B),         dim3(256), 0, stream, lpart, bcls, parts_out, agg_out);
}